// Round 8
// baseline (194.033 us; speedup 1.0000x reference)
//
#include <hip/hip_runtime.h>

typedef __bf16 bf16;
typedef __bf16 bf16x8 __attribute__((ext_vector_type(8)));
typedef __bf16 bf16x4 __attribute__((ext_vector_type(4)));
typedef float f32x4 __attribute__((ext_vector_type(4)));
typedef unsigned int uint;

// Problem constants
#define BB 4
#define TT 2048
#define CC 1024
#define HH 16
#define DD 64
#define MM (BB*TT)   // 8192

// softmax scale folded into q: 1/sqrt(64) * log2(e)  (we use exp2 in the kernel)
#define QSCALE (0.125f * 1.4426950408889634f)

#define MFMA_(a,b,c) __builtin_amdgcn_mfma_f32_16x16x32_bf16(a,b,c,0,0,0)

__device__ __forceinline__ void async_copy16(const bf16* g, bf16* l) {
    __builtin_amdgcn_global_load_lds((const __attribute__((address_space(1))) void*)g,
                                     (__attribute__((address_space(3))) void*)l, 16, 0, 0);
}

// single-instruction 2^x (libm exp2f without -ffast-math expands to ~12 insts)
__device__ __forceinline__ float ex2(float x) {
#if __has_builtin(__builtin_amdgcn_exp2f)
    return __builtin_amdgcn_exp2f(x);
#else
    float r; asm("v_exp_f32 %0, %1" : "=v"(r) : "v"(x)); return r;
#endif
}

// ---------------- convert f32 -> bf16 ----------------
__global__ void conv_f32_bf16(const float* __restrict__ in, bf16* __restrict__ out, int n) {
    int i = (blockIdx.x * blockDim.x + threadIdx.x) * 4;
    int stride = gridDim.x * blockDim.x * 4;
    for (; i < n; i += stride) {
        float4 v = *(const float4*)(in + i);
        bf16x4 o;
        o[0] = (bf16)v.x; o[1] = (bf16)v.y; o[2] = (bf16)v.z; o[3] = (bf16)v.w;
        *(bf16x4*)(out + i) = o;
    }
}

// ---------------- transpose + convert: in [K][N] f32 -> out [N][K] bf16 ----------------
__global__ void transpose_f32_bf16(const float* __restrict__ in, bf16* __restrict__ out,
                                   int K, int N) {
    __shared__ bf16 tile[64][65];
    int n0 = blockIdx.x * 64, k0 = blockIdx.y * 64;
    int tc = threadIdx.x & 63, tr = threadIdx.x >> 6;
    #pragma unroll
    for (int p = 0; p < 16; ++p) {
        int k = tr + p * 4;
        tile[k][tc] = (bf16)in[(size_t)(k0 + k) * N + n0 + tc];
    }
    __syncthreads();
    #pragma unroll
    for (int p = 0; p < 16; ++p) {
        int n = tr + p * 4;
        out[(size_t)(n0 + n) * K + k0 + tc] = tile[tc][n];
    }
}

// ---------------- GEMM: C[M][N] = A[M][K] @ Bt[N][K]^T + bias ----------------
// m201-class schedule: BM=BN=256, BK=32, 512 thr (8 waves 2Mx4N, per-wave C 128x64).
// 4-deep LDS tile ring (4 x 32KB). 2 phases per K-tile (m-quad split); per phase:
// {ds_read frags BEFORE barrier | stage 2 global_load_lds | barrier | 16 MFMA w/ setprio | barrier}.
// vmcnt(8) once per tile (3-tile lookahead, loads stay in flight across barriers).
// LDS rows 64B: stored granule g holds global granule g^(row&3); reads use l4^(l15&3).
// MODE 0: scatter q (xQSCALE) / k ([B*H][T][D]) / v^T ([B*H][D][T]); MODE 1: f32 [M][N].
// K must be 1024 (32 tiles: 29 steady + 3 epilogue).
template<int MODE>
__global__ __launch_bounds__(512, 2) void gemm9(
    const bf16* __restrict__ A, const bf16* __restrict__ Bt,
    const float* __restrict__ bias,
    void* __restrict__ out0, void* __restrict__ out1, void* __restrict__ out2,
    int M, int N, int K)
{
    __shared__ bf16 As[4][2][128 * 32];   // [buf][half][row*32+col]  64 KB
    __shared__ bf16 Bs[4][2][128 * 32];   // 64 KB

    // bijective XCD-chunked remap (nwg % 8 == 0: 384 / 128)
    int nwg = gridDim.x * gridDim.y;
    int id  = blockIdx.y * gridDim.x + blockIdx.x;
    int sid = (id & 7) * (nwg >> 3) + (id >> 3);
    int bx = sid % gridDim.x, by = sid / gridDim.x;

    const int tid = threadIdx.x;
    const int lane = tid & 63, w = tid >> 6;
    const int l15 = lane & 15, l4 = lane >> 4;
    const int wm = w >> 2, wn = w & 3;         // 2M x 4N waves
    const int hn = wn >> 1;                    // B half for this wave
    const int rb0 = (wn & 1) * 64;             // B row base within half
    const int gr8 = (l4 ^ (l15 & 3)) * 8;      // swizzled read granule (elems)
    const int wbase = w * 512;                 // wave's LDS stage base (elems)

    const bf16* Ab = A + (size_t)(by * 256) * K;
    const bf16* Bb = Bt + (size_t)(bx * 256) * K;
    const int srow = tid >> 2;                         // 0..127 (row within half)
    const int scol = ((tid & 3) ^ (srow & 3)) * 8;     // pre-swizzled source granule

    float bv[4];
    #pragma unroll
    for (int n = 0; n < 4; ++n)
        bv[n] = bias[bx * 256 + wn * 64 + n * 16 + l15];

    f32x4 acc[8][4] = {};

#define STAGE_A(SB, T) \
    async_copy16(Ab + (size_t)srow * K + (T) * 32 + scol,        &As[SB][0][wbase]); \
    async_copy16(Ab + (size_t)(128 + srow) * K + (T) * 32 + scol, &As[SB][1][wbase]);
#define STAGE_B(SB, T) \
    async_copy16(Bb + (size_t)srow * K + (T) * 32 + scol,        &Bs[SB][0][wbase]); \
    async_copy16(Bb + (size_t)(128 + srow) * K + (T) * 32 + scol, &Bs[SB][1][wbase]);

#define TILE_BODY(CU, SB, T3, DOSTAGE, VMC)                                        \
  {                                                                                \
    bf16x8 xa[4], xb[4];                                                           \
    _Pragma("unroll")                                                              \
    for (int mq = 0; mq < 4; ++mq)                                                 \
      xa[mq] = *(const bf16x8*)&As[CU][wm][(mq * 16 + l15) * 32 + gr8];            \
    _Pragma("unroll")                                                              \
    for (int n = 0; n < 4; ++n)                                                    \
      xb[n] = *(const bf16x8*)&Bs[CU][hn][(rb0 + n * 16 + l15) * 32 + gr8];        \
    if (DOSTAGE) { STAGE_A(SB, T3) }                                               \
    __builtin_amdgcn_sched_barrier(0);                                             \
    __builtin_amdgcn_s_barrier();                                                  \
    __builtin_amdgcn_sched_barrier(0);                                             \
    __builtin_amdgcn_s_setprio(1);                                                 \
    _Pragma("unroll")                                                              \
    for (int mq = 0; mq < 4; ++mq)                                                 \
      _Pragma("unroll")                                                            \
      for (int n = 0; n < 4; ++n)                                                  \
        acc[mq][n] = MFMA_(xa[mq], xb[n], acc[mq][n]);                             \
    __builtin_amdgcn_s_setprio(0);                                                 \
    __builtin_amdgcn_sched_barrier(0);                                             \
    __builtin_amdgcn_s_barrier();                                                  \
    __builtin_amdgcn_sched_barrier(0);                                             \
    _Pragma("unroll")                                                              \
    for (int mq = 0; mq < 4; ++mq)                                                 \
      xa[mq] = *(const bf16x8*)&As[CU][wm][((64 + mq * 16) + l15) * 32 + gr8];     \
    if (DOSTAGE) { STAGE_B(SB, T3) }                                               \
    asm volatile("s_waitcnt vmcnt(" VMC ")" ::: "memory");                         \
    __builtin_amdgcn_sched_barrier(0);                                             \
    __builtin_amdgcn_s_barrier();                                                  \
    __builtin_amdgcn_sched_barrier(0);                                             \
    __builtin_amdgcn_s_setprio(1);                                                 \
    _Pragma("unroll")                                                              \
    for (int mq = 0; mq < 4; ++mq)                                                 \
      _Pragma("unroll")                                                            \
      for (int n = 0; n < 4; ++n)                                                  \
        acc[4 + mq][n] = MFMA_(xa[mq], xb[n], acc[4 + mq][n]);                     \
    __builtin_amdgcn_s_setprio(0);                                                 \
    __builtin_amdgcn_sched_barrier(0);                                             \
    __builtin_amdgcn_s_barrier();                                                  \
    __builtin_amdgcn_sched_barrier(0);                                             \
  }

    // prologue: tiles 0,1,2 into bufs 0,1,2 (12 loads); validate tile 0
    STAGE_A(0, 0) STAGE_B(0, 0)
    STAGE_A(1, 1) STAGE_B(1, 1)
    STAGE_A(2, 2) STAGE_B(2, 2)
    asm volatile("s_waitcnt vmcnt(8)" ::: "memory");
    __builtin_amdgcn_s_barrier();

    // steady state: tiles 0..28, stage t+3, vmcnt(8) validates t+1
    for (int t = 0; t < 29; ++t) {
        int cu = t & 3, sb = (t + 3) & 3;
        TILE_BODY(cu, sb, t + 3, 1, "8");
    }
    // epilogue tiles 29,30,31 (no staging; drain 4 -> 0 -> 0)
    TILE_BODY(1, 0, 0, 0, "4");
    TILE_BODY(2, 0, 0, 0, "0");
    TILE_BODY(3, 0, 0, 0, "0");

#undef TILE_BODY
#undef STAGE_A
#undef STAGE_B

    if constexpr (MODE == 0) {
        int which = bx >> 2;     // 0=q 1=k 2=v (block is uniform; N=3072, BN=256)
        int b = by >> 3;
        #pragma unroll
        for (int n = 0; n < 4; ++n) {
            int col = bx * 256 + wn * 64 + n * 16 + l15;
            int c = col & 1023;
            int h = c >> 6, d = c & 63;
            size_t bh = (size_t)(b * HH + h);
            #pragma unroll
            for (int m = 0; m < 8; ++m) {
                int row = by * 256 + wm * 128 + m * 16 + l4 * 4;
                int t0 = row & 2047;
                if (which == 2) {
                    bf16x4 pk;
                    #pragma unroll
                    for (int i = 0; i < 4; ++i) pk[i] = (bf16)(acc[m][n][i] + bv[n]);
                    *(bf16x4*)((bf16*)out2 + (bh * DD + d) * TT + t0) = pk;
                } else {
                    bf16* dst = (bf16*)(which == 0 ? out0 : out1);
                    float sc = (which == 0) ? QSCALE : 1.f;
                    #pragma unroll
                    for (int i = 0; i < 4; ++i)
                        dst[(bh * TT + t0 + i) * DD + d] = (bf16)((acc[m][n][i] + bv[n]) * sc);
                }
            }
        }
    } else {
        #pragma unroll
        for (int m = 0; m < 8; ++m) {
            #pragma unroll
            for (int n = 0; n < 4; ++n) {
                int row = by * 256 + wm * 128 + m * 16 + l4 * 4;
                int col = bx * 256 + wn * 64 + n * 16 + l15;
                #pragma unroll
                for (int i = 0; i < 4; ++i)
                    ((float*)out0)[(size_t)(row + i) * N + col] = acc[m][n][i] + bv[n];
            }
        }
    }
}

// ---------------- causal flash attention (swapped-QK, dbuf, defer-max, in-reg P) ----------------
// Balanced pairing: grid y = 0..7; block processes q-tile (15-y) then (y):
// uniform 34 tiles per block, 512 equal blocks.
__global__ __launch_bounds__(256, 2) void attn_kernel(
    const bf16* __restrict__ Q, const bf16* __restrict__ Kb, const bf16* __restrict__ Vt,
    bf16* __restrict__ Y)
{
    constexpr int PD = 72;
    __shared__ bf16 Ks[2][64 * PD];   // [key][d]
    __shared__ bf16 Vs[2][64 * PD];   // [d][key]

    int bh = blockIdx.x;           // 0..63
    int b = bh >> 4, h = bh & 15;

    int tid = threadIdx.x;
    int lane = tid & 63, w = tid >> 6;
    int l15 = lane & 15, l4 = lane >> 4;

    const bf16* Qg = Q  + (size_t)bh * TT * DD;
    const bf16* Kg = Kb + (size_t)bh * TT * DD;
    const bf16* Vg = Vt + (size_t)bh * DD * TT;

    int sr = tid >> 3, sc = (tid & 7) * 8;

    #pragma unroll
    for (int part = 0; part < 2; ++part) {
        int qt = part == 0 ? (15 - (int)blockIdx.y) : (int)blockIdx.y;
        int q0 = qt * 128 + w * 32;    // wave's first q row

        bf16x8 qf[2][2];
        #pragma unroll
        for (int m = 0; m < 2; ++m)
            #pragma unroll
            for (int kk = 0; kk < 2; ++kk)
                qf[m][kk] = *(const bf16x8*)(Qg + (size_t)(q0 + m * 16 + l15) * DD + kk * 32 + l4 * 8);

        f32x4 o[2][4] = {};                 // o[mq][n]: q = q0+mq*16+l4*4+i, d = n*16+l15
        float mst[2] = {-1e30f, -1e30f};    // per q-row (ms, l15)
        float lst[2] = {0.f, 0.f};

        int NT = 2 * qt + 2;

        // incremental staging pointers
        const bf16* kp = Kg + (size_t)sr * DD + sc;
        const bf16* vp = Vg + (size_t)sr * TT + sc;
        bf16x8 kr0 = *(const bf16x8*)(kp);
        bf16x8 kr1 = *(const bf16x8*)(kp + 32 * DD);
        bf16x8 vr0 = *(const bf16x8*)(vp);
        bf16x8 vr1 = *(const bf16x8*)(vp + (size_t)32 * TT);
        kp += 64 * DD; vp += 64;

        for (int kt = 0; kt < NT; ++kt) {
            int buf = kt & 1;
            *(bf16x8*)(&Ks[buf][(size_t)sr * PD + sc])        = kr0;
            *(bf16x8*)(&Ks[buf][(size_t)(sr + 32) * PD + sc]) = kr1;
            *(bf16x8*)(&Vs[buf][(size_t)sr * PD + sc])        = vr0;
            *(bf16x8*)(&Vs[buf][(size_t)(sr + 32) * PD + sc]) = vr1;
            if (kt + 1 < NT) {
                kr0 = *(const bf16x8*)(kp);
                kr1 = *(const bf16x8*)(kp + 32 * DD);
                vr0 = *(const bf16x8*)(vp);
                vr1 = *(const bf16x8*)(vp + (size_t)32 * TT);
                kp += 64 * DD; vp += 64;
            }
            __syncthreads();

            if (kt * 64 <= q0 + 31) {
                int ktb = kt * 64;
                f32x4 s[2][4] = {};
                #pragma unroll
                for (int kk = 0; kk < 2; ++kk) {
                    bf16x8 kf[4];
                    #pragma unroll
                    for (int n = 0; n < 4; ++n)
                        kf[n] = *(const bf16x8*)(&Ks[buf][(n * 16 + l15) * PD + kk * 32 + l4 * 8]);
                    #pragma unroll
                    for (int ms = 0; ms < 2; ++ms)
                        #pragma unroll
                        for (int n = 0; n < 4; ++n)
                            s[ms][n] = __builtin_amdgcn_mfma_f32_16x16x32_bf16(kf[n], qf[ms][kk], s[ms][n], 0, 0, 0);
                }

                bf16x8 paf[2][2];
                #pragma unroll
                for (int ms = 0; ms < 2; ++ms) {
                    int qr = q0 + ms * 16 + l15;
                    if (ktb + 63 > q0 + ms * 16) {
                        #pragma unroll
                        for (int n = 0; n < 4; ++n) {
                            int keyb = ktb + n * 16 + l4 * 4;
                            #pragma unroll
                            for (int i = 0; i < 4; ++i)
                                if (keyb + i > qr) s[ms][n][i] = -1e30f;
                        }
                    }
                    float mx0 = fmaxf(fmaxf(s[ms][0][0], s[ms][0][1]), fmaxf(s[ms][0][2], s[ms][0][3]));
                    float mx1 = fmaxf(fmaxf(s[ms][1][0], s[ms][1][1]), fmaxf(s[ms][1][2], s[ms][1][3]));
                    float mx2 = fmaxf(fmaxf(s[ms][2][0], s[ms][2][1]), fmaxf(s[ms][2][2], s[ms][2][3]));
                    float mx3 = fmaxf(fmaxf(s[ms][3][0], s[ms][3][1]), fmaxf(s[ms][3][2], s[ms][3][3]));
                    float mx = fmaxf(fmaxf(mx0, mx1), fmaxf(mx2, mx3));
                    mx = fmaxf(mx, __shfl_xor(mx, 16));
                    mx = fmaxf(mx, __shfl_xor(mx, 32));

                    if (__any(mx > mst[ms] + 11.5f)) {
                        float mnew = fmaxf(mst[ms], mx);
                        float sc2 = ex2(mst[ms] - mnew);
                        mst[ms] = mnew;
                        lst[ms] *= sc2;
                        float scl[4];
                        #pragma unroll
                        for (int i = 0; i < 4; ++i) scl[i] = __shfl(sc2, l4 * 4 + i);
                        #pragma unroll
                        for (int n = 0; n < 4; ++n)
                            #pragma unroll
                            for (int i = 0; i < 4; ++i) o[ms][n][i] *= scl[i];
                    }

                    uint pk_[4][2];
                    float rs = 0.f;
                    #pragma unroll
                    for (int n = 0; n < 4; ++n) {
                        float p0 = ex2(s[ms][n][0] - mst[ms]);
                        float p1 = ex2(s[ms][n][1] - mst[ms]);
                        float p2 = ex2(s[ms][n][2] - mst[ms]);
                        float p3 = ex2(s[ms][n][3] - mst[ms]);
                        rs += (p0 + p1) + (p2 + p3);
                        asm("v_cvt_pk_bf16_f32 %0, %1, %2" : "=v"(pk_[n][0]) : "v"(p0), "v"(p1));
                        asm("v_cvt_pk_bf16_f32 %0, %1, %2" : "=v"(pk_[n][1]) : "v"(p2), "v"(p3));
                    }
                    rs += __shfl_xor(rs, 16);
                    rs += __shfl_xor(rs, 32);
                    lst[ms] += rs;

                    asm("v_permlane32_swap_b32 %0, %1" : "+v"(pk_[0][0]), "+v"(pk_[1][0]));
                    asm("v_permlane32_swap_b32 %0, %1" : "+v"(pk_[0][1]), "+v"(pk_[1][1]));
                    asm("v_permlane32_swap_b32 %0, %1" : "+v"(pk_[2][0]), "+v"(pk_[3][0]));
                    asm("v_permlane32_swap_b32 %0, %1" : "+v"(pk_[2][1]), "+v"(pk_[3][1]));
                    asm("v_permlane16_swap_b32 %0, %1" : "+v"(pk_[0][0]), "+v"(pk_[1][0]));
                    asm("v_permlane16_swap_b32 %0, %1" : "+v"(pk_[0][1]), "+v"(pk_[1][1]));
                    asm("v_permlane16_swap_b32 %0, %1" : "+v"(pk_[2][0]), "+v"(pk_[3][0]));
                    asm("v_permlane16_swap_b32 %0, %1" : "+v"(pk_[2][1]), "+v"(pk_[3][1]));
                    uint4 u0 = {pk_[0][0], pk_[0][1], pk_[1][0], pk_[1][1]};
                    uint4 u1 = {pk_[2][0], pk_[2][1], pk_[3][0], pk_[3][1]};
                    paf[ms][0] = __builtin_bit_cast(bf16x8, u0);
                    paf[ms][1] = __builtin_bit_cast(bf16x8, u1);
                }

                #pragma unroll
                for (int kk = 0; kk < 2; ++kk) {
                    bf16x8 vf[4];
                    #pragma unroll
                    for (int n = 0; n < 4; ++n)
                        vf[n] = *(const bf16x8*)(&Vs[buf][(n * 16 + l15) * PD + kk * 32 + l4 * 8]);
                    #pragma unroll
                    for (int mq = 0; mq < 2; ++mq)
                        #pragma unroll
                        for (int n = 0; n < 4; ++n)
                            o[mq][n] = __builtin_amdgcn_mfma_f32_16x16x32_bf16(paf[mq][kk], vf[n], o[mq][n], 0, 0, 0);
                }
            }
        }

        #pragma unroll
        for (int mq = 0; mq < 2; ++mq) {
            float inv[4];
            #pragma unroll
            for (int i = 0; i < 4; ++i) inv[i] = 1.f / __shfl(lst[mq], l4 * 4 + i);
            #pragma unroll
            for (int i = 0; i < 4; ++i) {
                int t = q0 + mq * 16 + l4 * 4 + i;
                #pragma unroll
                for (int n = 0; n < 4; ++n) {
                    int d = n * 16 + l15;
                    Y[((size_t)(b * TT + t)) * CC + h * DD + d] = (bf16)(o[mq][n][i] * inv[i]);
                }
            }
        }
    }
}

extern "C" void kernel_launch(void* const* d_in, const int* in_sizes, int n_in,
                              void* d_out, int out_size, void* d_ws, size_t ws_size,
                              hipStream_t stream) {
    const float* x      = (const float*)d_in[0];
    const float* w_attn = (const float*)d_in[1];
    const float* b_attn = (const float*)d_in[2];
    const float* w_proj = (const float*)d_in[3];
    const float* b_proj = (const float*)d_in[4];
    float* out = (float*)d_out;

    bf16* xb  = (bf16*)d_ws;                        // [8192][1024]
    bf16* waT = xb  + (size_t)MM * CC;              // [3072][1024]
    bf16* wpT = waT + (size_t)3 * CC * CC;          // [1024][1024]
    bf16* qb  = wpT + (size_t)CC * CC;              // [B*H][T][D]
    bf16* kb  = qb  + (size_t)MM * CC;              // [B*H][T][D]
    bf16* vt  = kb  + (size_t)MM * CC;              // [B*H][D][T] (written directly by gemm9<0>)
    bf16* yb  = vt  + (size_t)MM * CC;              // [8192][1024] attention output

    conv_f32_bf16<<<2048, 256, 0, stream>>>(x, xb, MM * CC);
    transpose_f32_bf16<<<dim3(3 * CC / 64, CC / 64), 256, 0, stream>>>(w_attn, waT, CC, 3 * CC);
    transpose_f32_bf16<<<dim3(CC / 64, CC / 64), 256, 0, stream>>>(w_proj, wpT, CC, CC);

    gemm9<0><<<dim3(3 * CC / 256, MM / 256), 512, 0, stream>>>(
        xb, waT, b_attn, qb, kb, vt, MM, 3 * CC, CC);

    attn_kernel<<<dim3(BB * HH, 8), 256, 0, stream>>>(qb, kb, vt, yb);

    gemm9<1><<<dim3(CC / 256, MM / 256), 512, 0, stream>>>(
        yb, wpT, b_proj, out, nullptr, nullptr, MM, CC, CC);
}

// Round 9
// 174.498 us; speedup vs baseline: 1.1119x; 1.1119x over previous
//
#include <hip/hip_runtime.h>

typedef __bf16 bf16;
typedef __bf16 bf16x8 __attribute__((ext_vector_type(8)));
typedef __bf16 bf16x4 __attribute__((ext_vector_type(4)));
typedef float f32x4 __attribute__((ext_vector_type(4)));
typedef unsigned int uint;

// Problem constants
#define BB 4
#define TT 2048
#define CC 1024
#define HH 16
#define DD 64
#define MM (BB*TT)   // 8192

// softmax scale folded into q: 1/sqrt(64) * log2(e)  (we use exp2 in the kernel)
#define QSCALE (0.125f * 1.4426950408889634f)

#define MFMA_(a,b,c) __builtin_amdgcn_mfma_f32_16x16x32_bf16(a,b,c,0,0,0)

__device__ __forceinline__ void async_copy16(const bf16* g, bf16* l) {
    __builtin_amdgcn_global_load_lds((const __attribute__((address_space(1))) void*)g,
                                     (__attribute__((address_space(3))) void*)l, 16, 0, 0);
}

// single-instruction 2^x (libm exp2f without -ffast-math expands to ~12 insts)
__device__ __forceinline__ float ex2(float x) {
#if __has_builtin(__builtin_amdgcn_exp2f)
    return __builtin_amdgcn_exp2f(x);
#else
    float r; asm("v_exp_f32 %0, %1" : "=v"(r) : "v"(x)); return r;
#endif
}

// ---------------- convert f32 -> bf16 ----------------
__global__ void conv_f32_bf16(const float* __restrict__ in, bf16* __restrict__ out, int n) {
    int i = (blockIdx.x * blockDim.x + threadIdx.x) * 4;
    int stride = gridDim.x * blockDim.x * 4;
    for (; i < n; i += stride) {
        float4 v = *(const float4*)(in + i);
        bf16x4 o;
        o[0] = (bf16)v.x; o[1] = (bf16)v.y; o[2] = (bf16)v.z; o[3] = (bf16)v.w;
        *(bf16x4*)(out + i) = o;
    }
}

// ---------------- transpose + convert: in [K][N] f32 -> out [N][K] bf16 ----------------
__global__ void transpose_f32_bf16(const float* __restrict__ in, bf16* __restrict__ out,
                                   int K, int N) {
    __shared__ bf16 tile[64][65];
    int n0 = blockIdx.x * 64, k0 = blockIdx.y * 64;
    int tc = threadIdx.x & 63, tr = threadIdx.x >> 6;
    #pragma unroll
    for (int p = 0; p < 16; ++p) {
        int k = tr + p * 4;
        tile[k][tc] = (bf16)in[(size_t)(k0 + k) * N + n0 + tc];
    }
    __syncthreads();
    #pragma unroll
    for (int p = 0; p < 16; ++p) {
        int n = tr + p * 4;
        out[(size_t)(n0 + n) * K + k0 + tc] = tile[tc][n];
    }
}

// ---------------- GEMM: C[M][N] = A[M][K] @ Bt[N][K]^T + bias ----------------
// 512 threads, BM=256 BN=128 BK=64, dbuf LDS. READS-FIRST schedule:
// per iter: {ds_read 16 frags of tile t (issued behind prior MFMA drain) |
// lgkm(0)+barrier (WAR gate) | stage t+2 into buf[t&1] | setprio+32 MFMA |
// vmcnt(6)+barrier validates t+1 under this MFMA drain}.
// LDS linear for global_load_lds; source granule pre-swizzled j=(lane&7)^(lane>>3),
// fragment reads XOR granule with (l15&7) -> 0 bank conflicts (measured r6).
// MODE 0: per-block scatter to q / k / v^T ([B*H][D][T]) bf16; q pre-scaled by QSCALE.
// MODE 1: write f32 out [M][N].  Requires K = 1024 (16 tiles).
template<int MODE>
__global__ __launch_bounds__(512, 2) void gemm8(
    const bf16* __restrict__ A, const bf16* __restrict__ Bt,
    const float* __restrict__ bias,
    void* __restrict__ out0, void* __restrict__ out1, void* __restrict__ out2,
    int M, int N, int K)
{
    constexpr int BM = 256, BN = 128, BK = 64;
    __shared__ bf16 As[2][BM * BK];   // 2 x 32 KB
    __shared__ bf16 Bs[2][BN * BK];   // 2 x 16 KB

    const int bx = blockIdx.x, by = blockIdx.y;
    const int tid = threadIdx.x;
    const int lane = tid & 63, w = tid >> 6;
    const int l15 = lane & 15, l4 = lane >> 4;
    const int wm = w >> 1, wn = w & 1;   // 4M x 2N waves; per-wave 64x64 C

    const bf16* Ab = A + (size_t)(by * BM) * K;
    const bf16* Bb = Bt + (size_t)(bx * BN) * K;

    const int srow = lane >> 3;
    const int scol = ((lane & 7) ^ srow) * 8;
    const int sx = l15 & 7;

    float bv[4];
    #pragma unroll
    for (int n = 0; n < 4; ++n)
        bv[n] = bias[bx * BN + wn * 64 + n * 16 + l15];

    f32x4 acc[4][4] = {};

#define STAGE(PAR, T)                                                              \
    {                                                                              \
        int k0 = (T) * BK;                                                         \
        _Pragma("unroll")                                                          \
        for (int i = 0; i < 4; ++i) {                                              \
            int rbase = i * 64 + w * 8;                                            \
            async_copy16(Ab + (size_t)(rbase + srow) * K + k0 + scol,              \
                         &As[PAR][rbase * BK]);                                    \
        }                                                                          \
        _Pragma("unroll")                                                          \
        for (int i = 0; i < 2; ++i) {                                              \
            int rbase = i * 64 + w * 8;                                            \
            async_copy16(Bb + (size_t)(rbase + srow) * K + k0 + scol,              \
                         &Bs[PAR][rbase * BK]);                                    \
        }                                                                          \
    }

#define READS(PAR)                                                                 \
    _Pragma("unroll")                                                              \
    for (int n = 0; n < 4; ++n)                                                    \
        _Pragma("unroll")                                                          \
        for (int kk = 0; kk < 2; ++kk)                                             \
            bfr[n][kk] = *(const bf16x8*)(&Bs[PAR][(wn * 64 + n * 16 + l15) * 64   \
                                                   + ((kk * 4 + l4) ^ sx) * 8]);   \
    _Pragma("unroll")                                                              \
    for (int m = 0; m < 4; ++m)                                                    \
        _Pragma("unroll")                                                          \
        for (int kk = 0; kk < 2; ++kk)                                             \
            afr[m][kk] = *(const bf16x8*)(&As[PAR][(wm * 64 + m * 16 + l15) * 64   \
                                                   + ((kk * 4 + l4) ^ sx) * 8]);

#define MFMA32                                                                     \
    __builtin_amdgcn_s_setprio(1);                                                 \
    _Pragma("unroll")                                                              \
    for (int kk = 0; kk < 2; ++kk)                                                 \
        _Pragma("unroll")                                                          \
        for (int m = 0; m < 4; ++m)                                                \
            _Pragma("unroll")                                                      \
            for (int n = 0; n < 4; ++n)                                            \
                acc[m][n] = MFMA_(afr[m][kk], bfr[n][kk], acc[m][n]);              \
    __builtin_amdgcn_s_setprio(0);

    // prologue: tiles 0,1 (6 loads each); bias(4) + t0(6) drain via vmcnt(6)
    STAGE(0, 0)
    STAGE(1, 1)
    asm volatile("s_waitcnt vmcnt(6)" ::: "memory");
    __builtin_amdgcn_sched_barrier(0);
    __builtin_amdgcn_s_barrier();
    __builtin_amdgcn_sched_barrier(0);

    // steady state: t = 0..13
    for (int t = 0; t < 14; ++t) {
        int par = t & 1;
        bf16x8 afr[4][2], bfr[4][2];
        READS(par)
        asm volatile("s_waitcnt lgkmcnt(0)" ::: "memory");
        __builtin_amdgcn_sched_barrier(0);
        __builtin_amdgcn_s_barrier();       // WAR gate: all reads of t done
        __builtin_amdgcn_sched_barrier(0);
        STAGE(par, t + 2)                   // overwrite buf[t&1] with t+2
        __builtin_amdgcn_sched_barrier(0);
        MFMA32
        __builtin_amdgcn_sched_barrier(0);
        asm volatile("s_waitcnt vmcnt(6)" ::: "memory");   // t+1 resident (t+2 in flight)
        __builtin_amdgcn_s_barrier();       // publish t+1, under MFMA drain
        __builtin_amdgcn_sched_barrier(0);
    }
    // t = 14: no staging; validate t15 with vmcnt(0)
    {
        bf16x8 afr[4][2], bfr[4][2];
        READS(0)
        asm volatile("s_waitcnt lgkmcnt(0)" ::: "memory");
        __builtin_amdgcn_sched_barrier(0);
        __builtin_amdgcn_s_barrier();
        __builtin_amdgcn_sched_barrier(0);
        MFMA32
        __builtin_amdgcn_sched_barrier(0);
        asm volatile("s_waitcnt vmcnt(0)" ::: "memory");
        __builtin_amdgcn_s_barrier();
        __builtin_amdgcn_sched_barrier(0);
    }
    // t = 15: tail
    {
        bf16x8 afr[4][2], bfr[4][2];
        READS(1)
        MFMA32
    }

#undef STAGE
#undef READS
#undef MFMA32

    if constexpr (MODE == 0) {
        int which = bx >> 3;     // 0=q 1=k 2=v (block is uniform)
        int b = by >> 3;
        #pragma unroll
        for (int n = 0; n < 4; ++n) {
            int col = bx * 128 + wn * 64 + n * 16 + l15;
            int c = col & 1023;
            int h = c >> 6, d = c & 63;
            size_t bh = (size_t)(b * HH + h);
            #pragma unroll
            for (int m = 0; m < 4; ++m) {
                int row = by * 256 + wm * 64 + m * 16 + l4 * 4;
                int t0 = row & 2047;
                if (which == 2) {
                    bf16x4 pk;
                    #pragma unroll
                    for (int i = 0; i < 4; ++i) pk[i] = (bf16)(acc[m][n][i] + bv[n]);
                    *(bf16x4*)((bf16*)out2 + (bh * DD + d) * TT + t0) = pk;
                } else {
                    bf16* dst = (bf16*)(which == 0 ? out0 : out1);
                    float sc = (which == 0) ? QSCALE : 1.f;
                    #pragma unroll
                    for (int i = 0; i < 4; ++i)
                        dst[(bh * TT + t0 + i) * DD + d] = (bf16)((acc[m][n][i] + bv[n]) * sc);
                }
            }
        }
    } else {
        #pragma unroll
        for (int m = 0; m < 4; ++m) {
            #pragma unroll
            for (int n = 0; n < 4; ++n) {
                int row = by * 256 + wm * 64 + m * 16 + l4 * 4;
                int col = bx * 128 + wn * 64 + n * 16 + l15;
                #pragma unroll
                for (int i = 0; i < 4; ++i)
                    ((float*)out0)[(size_t)(row + i) * N + col] = acc[m][n][i] + bv[n];
            }
        }
    }
}

// ---------------- causal flash attention (swapped-QK, dbuf, defer-max, in-reg P) ----------------
// Balanced pairing: grid y = 0..7; block processes q-tile (15-y) then (y):
// uniform 34 tiles per block, 512 equal blocks.
__global__ __launch_bounds__(256, 2) void attn_kernel(
    const bf16* __restrict__ Q, const bf16* __restrict__ Kb, const bf16* __restrict__ Vt,
    bf16* __restrict__ Y)
{
    constexpr int PD = 72;
    __shared__ bf16 Ks[2][64 * PD];   // [key][d]
    __shared__ bf16 Vs[2][64 * PD];   // [d][key]

    int bh = blockIdx.x;           // 0..63
    int b = bh >> 4, h = bh & 15;

    int tid = threadIdx.x;
    int lane = tid & 63, w = tid >> 6;
    int l15 = lane & 15, l4 = lane >> 4;

    const bf16* Qg = Q  + (size_t)bh * TT * DD;
    const bf16* Kg = Kb + (size_t)bh * TT * DD;
    const bf16* Vg = Vt + (size_t)bh * DD * TT;

    int sr = tid >> 3, sc = (tid & 7) * 8;

    #pragma unroll
    for (int part = 0; part < 2; ++part) {
        int qt = part == 0 ? (15 - (int)blockIdx.y) : (int)blockIdx.y;
        int q0 = qt * 128 + w * 32;    // wave's first q row

        bf16x8 qf[2][2];
        #pragma unroll
        for (int m = 0; m < 2; ++m)
            #pragma unroll
            for (int kk = 0; kk < 2; ++kk)
                qf[m][kk] = *(const bf16x8*)(Qg + (size_t)(q0 + m * 16 + l15) * DD + kk * 32 + l4 * 8);

        f32x4 o[2][4] = {};                 // o[mq][n]: q = q0+mq*16+l4*4+i, d = n*16+l15
        float mst[2] = {-1e30f, -1e30f};    // per q-row (ms, l15)
        float lst[2] = {0.f, 0.f};

        int NT = 2 * qt + 2;

        // incremental staging pointers
        const bf16* kp = Kg + (size_t)sr * DD + sc;
        const bf16* vp = Vg + (size_t)sr * TT + sc;
        bf16x8 kr0 = *(const bf16x8*)(kp);
        bf16x8 kr1 = *(const bf16x8*)(kp + 32 * DD);
        bf16x8 vr0 = *(const bf16x8*)(vp);
        bf16x8 vr1 = *(const bf16x8*)(vp + (size_t)32 * TT);
        kp += 64 * DD; vp += 64;

        for (int kt = 0; kt < NT; ++kt) {
            int buf = kt & 1;
            *(bf16x8*)(&Ks[buf][(size_t)sr * PD + sc])        = kr0;
            *(bf16x8*)(&Ks[buf][(size_t)(sr + 32) * PD + sc]) = kr1;
            *(bf16x8*)(&Vs[buf][(size_t)sr * PD + sc])        = vr0;
            *(bf16x8*)(&Vs[buf][(size_t)(sr + 32) * PD + sc]) = vr1;
            if (kt + 1 < NT) {
                kr0 = *(const bf16x8*)(kp);
                kr1 = *(const bf16x8*)(kp + 32 * DD);
                vr0 = *(const bf16x8*)(vp);
                vr1 = *(const bf16x8*)(vp + (size_t)32 * TT);
                kp += 64 * DD; vp += 64;
            }
            __syncthreads();

            if (kt * 64 <= q0 + 31) {
                int ktb = kt * 64;
                f32x4 s[2][4] = {};
                #pragma unroll
                for (int kk = 0; kk < 2; ++kk) {
                    bf16x8 kf[4];
                    #pragma unroll
                    for (int n = 0; n < 4; ++n)
                        kf[n] = *(const bf16x8*)(&Ks[buf][(n * 16 + l15) * PD + kk * 32 + l4 * 8]);
                    #pragma unroll
                    for (int ms = 0; ms < 2; ++ms)
                        #pragma unroll
                        for (int n = 0; n < 4; ++n)
                            s[ms][n] = __builtin_amdgcn_mfma_f32_16x16x32_bf16(kf[n], qf[ms][kk], s[ms][n], 0, 0, 0);
                }

                bf16x8 paf[2][2];
                #pragma unroll
                for (int ms = 0; ms < 2; ++ms) {
                    int qr = q0 + ms * 16 + l15;
                    if (ktb + 63 > q0 + ms * 16) {
                        #pragma unroll
                        for (int n = 0; n < 4; ++n) {
                            int keyb = ktb + n * 16 + l4 * 4;
                            #pragma unroll
                            for (int i = 0; i < 4; ++i)
                                if (keyb + i > qr) s[ms][n][i] = -1e30f;
                        }
                    }
                    float mx0 = fmaxf(fmaxf(s[ms][0][0], s[ms][0][1]), fmaxf(s[ms][0][2], s[ms][0][3]));
                    float mx1 = fmaxf(fmaxf(s[ms][1][0], s[ms][1][1]), fmaxf(s[ms][1][2], s[ms][1][3]));
                    float mx2 = fmaxf(fmaxf(s[ms][2][0], s[ms][2][1]), fmaxf(s[ms][2][2], s[ms][2][3]));
                    float mx3 = fmaxf(fmaxf(s[ms][3][0], s[ms][3][1]), fmaxf(s[ms][3][2], s[ms][3][3]));
                    float mx = fmaxf(fmaxf(mx0, mx1), fmaxf(mx2, mx3));
                    mx = fmaxf(mx, __shfl_xor(mx, 16));
                    mx = fmaxf(mx, __shfl_xor(mx, 32));

                    if (__any(mx > mst[ms] + 11.5f)) {
                        float mnew = fmaxf(mst[ms], mx);
                        float sc2 = ex2(mst[ms] - mnew);
                        mst[ms] = mnew;
                        lst[ms] *= sc2;
                        float scl[4];
                        #pragma unroll
                        for (int i = 0; i < 4; ++i) scl[i] = __shfl(sc2, l4 * 4 + i);
                        #pragma unroll
                        for (int n = 0; n < 4; ++n)
                            #pragma unroll
                            for (int i = 0; i < 4; ++i) o[ms][n][i] *= scl[i];
                    }

                    uint pk_[4][2];
                    float rs = 0.f;
                    #pragma unroll
                    for (int n = 0; n < 4; ++n) {
                        float p0 = ex2(s[ms][n][0] - mst[ms]);
                        float p1 = ex2(s[ms][n][1] - mst[ms]);
                        float p2 = ex2(s[ms][n][2] - mst[ms]);
                        float p3 = ex2(s[ms][n][3] - mst[ms]);
                        rs += (p0 + p1) + (p2 + p3);
                        asm("v_cvt_pk_bf16_f32 %0, %1, %2" : "=v"(pk_[n][0]) : "v"(p0), "v"(p1));
                        asm("v_cvt_pk_bf16_f32 %0, %1, %2" : "=v"(pk_[n][1]) : "v"(p2), "v"(p3));
                    }
                    rs += __shfl_xor(rs, 16);
                    rs += __shfl_xor(rs, 32);
                    lst[ms] += rs;

                    asm("v_permlane32_swap_b32 %0, %1" : "+v"(pk_[0][0]), "+v"(pk_[1][0]));
                    asm("v_permlane32_swap_b32 %0, %1" : "+v"(pk_[0][1]), "+v"(pk_[1][1]));
                    asm("v_permlane32_swap_b32 %0, %1" : "+v"(pk_[2][0]), "+v"(pk_[3][0]));
                    asm("v_permlane32_swap_b32 %0, %1" : "+v"(pk_[2][1]), "+v"(pk_[3][1]));
                    asm("v_permlane16_swap_b32 %0, %1" : "+v"(pk_[0][0]), "+v"(pk_[1][0]));
                    asm("v_permlane16_swap_b32 %0, %1" : "+v"(pk_[0][1]), "+v"(pk_[1][1]));
                    asm("v_permlane16_swap_b32 %0, %1" : "+v"(pk_[2][0]), "+v"(pk_[3][0]));
                    asm("v_permlane16_swap_b32 %0, %1" : "+v"(pk_[2][1]), "+v"(pk_[3][1]));
                    uint4 u0 = {pk_[0][0], pk_[0][1], pk_[1][0], pk_[1][1]};
                    uint4 u1 = {pk_[2][0], pk_[2][1], pk_[3][0], pk_[3][1]};
                    paf[ms][0] = __builtin_bit_cast(bf16x8, u0);
                    paf[ms][1] = __builtin_bit_cast(bf16x8, u1);
                }

                #pragma unroll
                for (int kk = 0; kk < 2; ++kk) {
                    bf16x8 vf[4];
                    #pragma unroll
                    for (int n = 0; n < 4; ++n)
                        vf[n] = *(const bf16x8*)(&Vs[buf][(n * 16 + l15) * PD + kk * 32 + l4 * 8]);
                    #pragma unroll
                    for (int mq = 0; mq < 2; ++mq)
                        #pragma unroll
                        for (int n = 0; n < 4; ++n)
                            o[mq][n] = __builtin_amdgcn_mfma_f32_16x16x32_bf16(paf[mq][kk], vf[n], o[mq][n], 0, 0, 0);
                }
            }
        }

        #pragma unroll
        for (int mq = 0; mq < 2; ++mq) {
            float inv[4];
            #pragma unroll
            for (int i = 0; i < 4; ++i) inv[i] = 1.f / __shfl(lst[mq], l4 * 4 + i);
            #pragma unroll
            for (int i = 0; i < 4; ++i) {
                int t = q0 + mq * 16 + l4 * 4 + i;
                #pragma unroll
                for (int n = 0; n < 4; ++n) {
                    int d = n * 16 + l15;
                    Y[((size_t)(b * TT + t)) * CC + h * DD + d] = (bf16)(o[mq][n][i] * inv[i]);
                }
            }
        }
    }
}

extern "C" void kernel_launch(void* const* d_in, const int* in_sizes, int n_in,
                              void* d_out, int out_size, void* d_ws, size_t ws_size,
                              hipStream_t stream) {
    const float* x      = (const float*)d_in[0];
    const float* w_attn = (const float*)d_in[1];
    const float* b_attn = (const float*)d_in[2];
    const float* w_proj = (const float*)d_in[3];
    const float* b_proj = (const float*)d_in[4];
    float* out = (float*)d_out;

    bf16* xb  = (bf16*)d_ws;                        // [8192][1024]
    bf16* waT = xb  + (size_t)MM * CC;              // [3072][1024]
    bf16* wpT = waT + (size_t)3 * CC * CC;          // [1024][1024]
    bf16* qb  = wpT + (size_t)CC * CC;              // [B*H][T][D]
    bf16* kb  = qb  + (size_t)MM * CC;              // [B*H][T][D]
    bf16* vt  = kb  + (size_t)MM * CC;              // [B*H][D][T] (written directly by gemm8<0>)
    bf16* yb  = vt  + (size_t)MM * CC;              // [8192][1024] attention output

    conv_f32_bf16<<<2048, 256, 0, stream>>>(x, xb, MM * CC);
    transpose_f32_bf16<<<dim3(3 * CC / 64, CC / 64), 256, 0, stream>>>(w_attn, waT, CC, 3 * CC);
    transpose_f32_bf16<<<dim3(CC / 64, CC / 64), 256, 0, stream>>>(w_proj, wpT, CC, CC);

    gemm8<0><<<dim3(3 * CC / 128, MM / 256), 512, 0, stream>>>(
        xb, waT, b_attn, qb, kb, vt, MM, 3 * CC, CC);

    attn_kernel<<<dim3(BB * HH, 8), 256, 0, stream>>>(qb, kb, vt, yb);

    gemm8<1><<<dim3(CC / 128, MM / 256), 512, 0, stream>>>(
        yb, wpT, b_proj, out, nullptr, nullptr, MM, CC, CC);
}